// Round 1
// baseline (224.448 us; speedup 1.0000x reference)
//
#include <hip/hip_runtime.h>
#include <math.h>

// Problem constants (match reference)
constexpr int cB = 2, cN = 8192, cS = 4096;
constexpr int cGEN = 28;   // 6 + 6 + 16 feature channels

// ---- distance helpers: EXACTLY mirror reference arithmetic ----
// ref: sq = (x*x + y*y) + z*z ; d2 = (sq_i + sq_j) - 2*dot ; d = sqrt(max(d2,1e-12))
// __f*_rn intrinsics block FMA contraction so rounding matches numpy f32.
__device__ __forceinline__ float d2clamp_rn(const float4 a, const float4 b) {
  float dot = __fadd_rn(__fadd_rn(__fmul_rn(a.x, b.x), __fmul_rn(a.y, b.y)), __fmul_rn(a.z, b.z));
  float d2  = __fsub_rn(__fadd_rn(a.w, b.w), __fmul_rn(2.0f, dot));
  return fmaxf(d2, 1e-12f);
}
__device__ __forceinline__ float dist_rn(const float4 a, const float4 b) {
  return sqrtf(d2clamp_rn(a, b));
}

__device__ __forceinline__ void ce64(unsigned long long& a, unsigned long long& b) {
  unsigned long long lo = a < b ? a : b;
  unsigned long long hi = a < b ? b : a;
  a = lo; b = hi;
}

// ---- K1: pack P[b][n] = (x,y,z,sq); SP[b][s] = packed sampled; emit sampled_xyz ----
__global__ __launch_bounds__(256) void pack_kernel(const float* __restrict__ xyz,
                                                   const int* __restrict__ smp,
                                                   float4* __restrict__ P,
                                                   float4* __restrict__ SP,
                                                   float* __restrict__ oxyz) {
  int t = blockIdx.x * 256 + threadIdx.x;
  if (t < cB * cN) {
    const float* p = xyz + t * 3;
    float x = p[0], y = p[1], z = p[2];
    float sq = __fadd_rn(__fadd_rn(__fmul_rn(x, x), __fmul_rn(y, y)), __fmul_rn(z, z));
    P[t] = make_float4(x, y, z, sq);
  } else if (t < cB * cN + cB * cS) {
    int j = t - cB * cN;           // j = b*cS + s
    int b = j >> 12;
    int idx = smp[j];
    const float* p = xyz + (b * cN + idx) * 3;
    float x = p[0], y = p[1], z = p[2];
    float sq = __fadd_rn(__fadd_rn(__fmul_rn(x, x), __fmul_rn(y, y)), __fmul_rn(z, z));
    SP[j] = make_float4(x, y, z, sq);
    oxyz[j * 3 + 0] = x; oxyz[j * 3 + 1] = y; oxyz[j * 3 + 2] = z;  // output 0
  }
}

// ---- K2: 4-NN of each sampled query over all N points; emit channels 0..5 + anchors_before ----
__global__ __launch_bounds__(256) void knn_before_kernel(const float4* __restrict__ P,
                                                         const int* __restrict__ smp,
                                                         float* __restrict__ trans,
                                                         int* __restrict__ AB) {
  int gid  = blockIdx.x * 256 + threadIdx.x;
  int w    = gid >> 6;                 // query id in [0, B*S)
  int lane = threadIdx.x & 63;
  int b    = w >> 12;
  int qi   = smp[w];
  const float4* Pb = P + b * cN;
  float4 pq = Pb[qi];

  unsigned long long k0 = ~0ull, k1 = ~0ull, k2 = ~0ull, k3 = ~0ull;
  for (int m = lane; m < cN; m += 64) {
    float c2 = d2clamp_rn(pq, Pb[m]);
    unsigned long long key =
        ((unsigned long long)__float_as_uint(c2) << 32) | (unsigned long long)(unsigned)m;
    if (key < k3) {                    // sorted insert, ascending (d2, idx)
      k3 = key;
      ce64(k2, k3); ce64(k1, k2); ce64(k0, k1);
    }
  }
  // 64-lane butterfly merge of sorted-4 lists (bitonic lower-half + sort4)
  #pragma unroll
  for (int off = 1; off < 64; off <<= 1) {
    unsigned long long b0 = __shfl_xor(k0, off, 64);
    unsigned long long b1 = __shfl_xor(k1, off, 64);
    unsigned long long b2 = __shfl_xor(k2, off, 64);
    unsigned long long b3 = __shfl_xor(k3, off, 64);
    unsigned long long m0 = k0 < b3 ? k0 : b3;
    unsigned long long m1 = k1 < b2 ? k1 : b2;
    unsigned long long m2 = k2 < b1 ? k2 : b1;
    unsigned long long m3 = k3 < b0 ? k3 : b0;
    ce64(m0, m2); ce64(m1, m3); ce64(m0, m1); ce64(m2, m3);
    k0 = m0; k1 = m1; k2 = m2; k3 = m3;
  }
  if (lane == 0) {
    int a0 = (int)(unsigned)k0, a1 = (int)(unsigned)k1;
    int a2 = (int)(unsigned)k2, a3 = (int)(unsigned)k3;
    float d1 = sqrtf(__uint_as_float((unsigned)(k1 >> 32)));
    float d2 = sqrtf(__uint_as_float((unsigned)(k2 >> 32)));
    float d3 = sqrtf(__uint_as_float((unsigned)(k3 >> 32)));
    float4 p1 = Pb[a1], p2 = Pb[a2], p3 = Pb[a3];
    float* tr = trans + w * cGEN;
    tr[0] = d1; tr[1] = d2; tr[2] = d3;
    tr[3] = dist_rn(p1, p2); tr[4] = dist_rn(p1, p3); tr[5] = dist_rn(p2, p3);
    int* ab = AB + w * 4;
    ab[0] = a0; ab[1] = a1; ab[2] = a2; ab[3] = a3;
  }
}

// ---- K3: 4-NN among sampled points; emit channels 6..11 + anchors_after (original idx) ----
__global__ __launch_bounds__(256) void knn_after_kernel(const float4* __restrict__ SP,
                                                        const int* __restrict__ smp,
                                                        float* __restrict__ trans,
                                                        int* __restrict__ AA) {
  int gid  = blockIdx.x * 256 + threadIdx.x;
  int w    = gid >> 6;
  int lane = threadIdx.x & 63;
  int b    = w >> 12;
  int s    = w & (cS - 1);
  const float4* Sb = SP + b * cS;
  float4 pq = Sb[s];

  unsigned long long k0 = ~0ull, k1 = ~0ull, k2 = ~0ull, k3 = ~0ull;
  for (int m = lane; m < cS; m += 64) {
    float c2 = d2clamp_rn(pq, Sb[m]);
    unsigned long long key =
        ((unsigned long long)__float_as_uint(c2) << 32) | (unsigned long long)(unsigned)m;
    if (key < k3) {
      k3 = key;
      ce64(k2, k3); ce64(k1, k2); ce64(k0, k1);
    }
  }
  #pragma unroll
  for (int off = 1; off < 64; off <<= 1) {
    unsigned long long b0 = __shfl_xor(k0, off, 64);
    unsigned long long b1 = __shfl_xor(k1, off, 64);
    unsigned long long b2 = __shfl_xor(k2, off, 64);
    unsigned long long b3 = __shfl_xor(k3, off, 64);
    unsigned long long m0 = k0 < b3 ? k0 : b3;
    unsigned long long m1 = k1 < b2 ? k1 : b2;
    unsigned long long m2 = k2 < b1 ? k2 : b1;
    unsigned long long m3 = k3 < b0 ? k3 : b0;
    ce64(m0, m2); ce64(m1, m3); ce64(m0, m1); ce64(m2, m3);
    k0 = m0; k1 = m1; k2 = m2; k3 = m3;
  }
  if (lane == 0) {
    int t0 = (int)(unsigned)k0, t1 = (int)(unsigned)k1;
    int t2 = (int)(unsigned)k2, t3 = (int)(unsigned)k3;
    float d1 = sqrtf(__uint_as_float((unsigned)(k1 >> 32)));
    float d2 = sqrtf(__uint_as_float((unsigned)(k2 >> 32)));
    float d3 = sqrtf(__uint_as_float((unsigned)(k3 >> 32)));
    float4 p1 = Sb[t1], p2 = Sb[t2], p3 = Sb[t3];
    float* tr = trans + w * cGEN;
    tr[6] = d1; tr[7] = d2; tr[8] = d3;
    tr[9] = dist_rn(p1, p2); tr[10] = dist_rn(p1, p3); tr[11] = dist_rn(p2, p3);
    const int* sb = smp + b * cS;
    int* aa = AA + w * 4;
    aa[0] = sb[t0]; aa[1] = sb[t1]; aa[2] = sb[t2]; aa[3] = sb[t3];
  }
}

// ---- K4: inter distances, channels 12..27: d(AB[a], AA[bb]), c = a*4+bb ----
__global__ __launch_bounds__(256) void inter_kernel(const float4* __restrict__ P,
                                                    const int* __restrict__ AB,
                                                    const int* __restrict__ AA,
                                                    float* __restrict__ trans) {
  int t = blockIdx.x * 256 + threadIdx.x;   // < B*S*16
  int w = t >> 4, c = t & 15;
  int b = w >> 12;
  int i = AB[w * 4 + (c >> 2)];
  int j = AA[w * 4 + (c & 3)];
  const float4* Pb = P + b * cN;
  trans[w * cGEN + 12 + c] = dist_rn(Pb[i], Pb[j]);
}

// ---- K5: MLP layers 1+2 fused (28->64->64); weights in LDS; wave = one query ----
__global__ __launch_bounds__(256) void mlp12_kernel(const float* __restrict__ trans,
                                                    const float* __restrict__ w1, const float* __restrict__ b1,
                                                    const float* __restrict__ g1, const float* __restrict__ be1,
                                                    const float* __restrict__ w2, const float* __restrict__ b2,
                                                    const float* __restrict__ g2, const float* __restrict__ be2,
                                                    float* __restrict__ T2) {
  __shared__ float sw1[28 * 64];
  __shared__ float sw2[64 * 64];
  __shared__ float sact[4][64];
  __shared__ float sp[6 * 64];
  for (int i = threadIdx.x; i < 28 * 64; i += 256) sw1[i] = w1[i];
  for (int i = threadIdx.x; i < 64 * 64; i += 256) sw2[i] = w2[i];
  if (threadIdx.x < 64) {
    int c = threadIdx.x;
    sp[c] = b1[c]; sp[64 + c] = g1[c]; sp[128 + c] = be1[c];
    sp[192 + c] = b2[c]; sp[256 + c] = g2[c]; sp[320 + c] = be2[c];
  }
  int t = blockIdx.x * 256 + threadIdx.x;
  int q = t >> 6, c = t & 63, qq = threadIdx.x >> 6;
  float tv = (c < cGEN) ? trans[q * cGEN + c] : 0.0f;
  __syncthreads();
  if (c < cGEN) sact[qq][c] = tv;
  __syncthreads();
  const float inv = 1.0f / sqrtf(1.0f + 1e-5f);
  float acc = 0.0f;
  #pragma unroll
  for (int k = 0; k < cGEN; k++) acc = fmaf(sact[qq][k], sw1[k * 64 + c], acc);
  float x = acc + sp[c];
  x = fmaf(x, sp[64 + c] * inv, sp[128 + c]);
  x = x >= 0.0f ? x : 0.2f * x;
  __syncthreads();
  sact[qq][c] = x;
  __syncthreads();
  acc = 0.0f;
  #pragma unroll
  for (int k = 0; k < 64; k++) acc = fmaf(sact[qq][k], sw2[k * 64 + c], acc);
  x = acc + sp[192 + c];
  x = fmaf(x, sp[256 + c] * inv, sp[320 + c]);
  x = x >= 0.0f ? x : 0.2f * x;
  T2[t] = x;
}

// ---- K6: MLP layer 3 (concat(feature, t2) -> 128); acts in LDS, w3 from L2 ----
__global__ __launch_bounds__(256) void mlp3_kernel(const float* __restrict__ feat,
                                                   const int* __restrict__ smp,
                                                   const float* __restrict__ T2,
                                                   const float* __restrict__ w3, const float* __restrict__ b3,
                                                   const float* __restrict__ g3, const float* __restrict__ be3,
                                                   float* __restrict__ out) {
  __shared__ float sact[2][128];
  int qq = threadIdx.x >> 7, c = threadIdx.x & 127;
  int q = blockIdx.x * 2 + qq;       // query in [0, B*S)
  int b = q >> 12;
  int srow = smp[q];
  sact[qq][c] = (c < 64) ? feat[(b * cN + srow) * 64 + c] : T2[q * 64 + (c - 64)];
  __syncthreads();
  const float inv = 1.0f / sqrtf(1.0f + 1e-5f);
  float acc = 0.0f;
  #pragma unroll 8
  for (int k = 0; k < 128; k++) acc = fmaf(sact[qq][k], w3[k * 128 + c], acc);
  float x = acc + b3[c];
  x = fmaf(x, g3[c] * inv, be3[c]);
  x = x >= 0.0f ? x : 0.2f * x;
  out[q * 128 + c] = x;
}

extern "C" void kernel_launch(void* const* d_in, const int* in_sizes, int n_in,
                              void* d_out, int out_size, void* d_ws, size_t ws_size,
                              hipStream_t stream) {
  const float* xyz  = (const float*)d_in[0];
  const float* feat = (const float*)d_in[1];
  const int*   smp  = (const int*)d_in[2];
  const float* w1   = (const float*)d_in[3];
  const float* b1   = (const float*)d_in[4];
  const float* g1   = (const float*)d_in[5];
  const float* be1  = (const float*)d_in[6];
  const float* w2   = (const float*)d_in[7];
  const float* b2   = (const float*)d_in[8];
  const float* g2   = (const float*)d_in[9];
  const float* be2  = (const float*)d_in[10];
  const float* w3   = (const float*)d_in[11];
  const float* b3   = (const float*)d_in[12];
  const float* g3   = (const float*)d_in[13];
  const float* be3  = (const float*)d_in[14];
  float* out = (float*)d_out;

  char* ws = (char*)d_ws;
  float4* P  = (float4*)(ws);                     // B*N*16   = 262144 B
  float4* SP = (float4*)(ws + 262144);            // B*S*16   = 131072 B
  float*  TR = (float*)(ws + 393216);             // B*S*28*4 = 917504 B
  int*    AB = (int*)(ws + 1310720);              // B*S*4*4  = 131072 B
  int*    AA = (int*)(ws + 1441792);              // B*S*4*4  = 131072 B
  float*  T2 = (float*)(ws + 1572864);            // B*S*64*4 = 2097152 B

  pack_kernel<<<96, 256, 0, stream>>>(xyz, smp, P, SP, out);
  knn_before_kernel<<<(cB * cS * 64) / 256, 256, 0, stream>>>(P, smp, TR, AB);
  knn_after_kernel<<<(cB * cS * 64) / 256, 256, 0, stream>>>(SP, smp, TR, AA);
  inter_kernel<<<(cB * cS * 16) / 256, 256, 0, stream>>>(P, AB, AA, TR);
  mlp12_kernel<<<(cB * cS * 64) / 256, 256, 0, stream>>>(TR, w1, b1, g1, be1, w2, b2, g2, be2, T2);
  mlp3_kernel<<<(cB * cS) / 2, 256, 0, stream>>>(feat, smp, T2, w3, b3, g3, be3, out + cB * cS * 3);
}

// Round 2
// 195.346 us; speedup vs baseline: 1.1490x; 1.1490x over previous
//
#include <hip/hip_runtime.h>
#include <math.h>

// Problem constants (match reference)
constexpr int cB = 2, cN = 8192, cS = 4096;
constexpr int cTR = 12;    // stored trans channels (0-5 before, 6-11 after); 12-27 computed in MLP

// ---- distance helpers: EXACTLY mirror reference arithmetic ----
// ref: sq = (x*x + y*y) + z*z ; d2 = (sq_i + sq_j) - 2*dot ; d = sqrt(max(d2,1e-12))
// __f*_rn intrinsics block FMA contraction so rounding matches numpy f32.
__device__ __forceinline__ float d2clamp_rn(const float4 a, const float4 b) {
  float dot = __fadd_rn(__fadd_rn(__fmul_rn(a.x, b.x), __fmul_rn(a.y, b.y)), __fmul_rn(a.z, b.z));
  float d2  = __fsub_rn(__fadd_rn(a.w, b.w), __fmul_rn(2.0f, dot));
  return fmaxf(d2, 1e-12f);
}
__device__ __forceinline__ float dist_rn(const float4 a, const float4 b) {
  return sqrtf(d2clamp_rn(a, b));
}

__device__ __forceinline__ void ce64(unsigned long long& a, unsigned long long& b) {
  unsigned long long lo = a < b ? a : b;
  unsigned long long hi = a < b ? b : a;
  a = lo; b = hi;
}

// ---- K1: pack P[b][n] = (x,y,z,sq); SP[b][s] = packed sampled; emit sampled_xyz ----
__global__ __launch_bounds__(256) void pack_kernel(const float* __restrict__ xyz,
                                                   const int* __restrict__ smp,
                                                   float4* __restrict__ P,
                                                   float4* __restrict__ SP,
                                                   float* __restrict__ oxyz) {
  int t = blockIdx.x * 256 + threadIdx.x;
  if (t < cB * cN) {
    const float* p = xyz + t * 3;
    float x = p[0], y = p[1], z = p[2];
    float sq = __fadd_rn(__fadd_rn(__fmul_rn(x, x), __fmul_rn(y, y)), __fmul_rn(z, z));
    P[t] = make_float4(x, y, z, sq);
  } else if (t < cB * cN + cB * cS) {
    int j = t - cB * cN;           // j = b*cS + s
    int b = j >> 12;
    int idx = smp[j];
    const float* p = xyz + (b * cN + idx) * 3;
    float x = p[0], y = p[1], z = p[2];
    float sq = __fadd_rn(__fadd_rn(__fmul_rn(x, x), __fmul_rn(y, y)), __fmul_rn(z, z));
    SP[j] = make_float4(x, y, z, sq);
    oxyz[j * 3 + 0] = x; oxyz[j * 3 + 1] = y; oxyz[j * 3 + 2] = z;  // output 0
  }
}

// ---- K2/K3: 4-NN, wave = one query, branchless float top-4, LDS-tiled candidates ----
// MODE 0: query = P[smp[wq]], candidates = P (CN=8192), trans ch0-5, Aout = raw ids
// MODE 1: query = SP[s],      candidates = SP (CN=4096), trans ch6-11, Aout = smp[id]
template <int MODE, int CN>
__global__ __launch_bounds__(256) void knn_kernel(const float4* __restrict__ Pts,
                                                  const int* __restrict__ smp,
                                                  float* __restrict__ trans,
                                                  int* __restrict__ Aout) {
  __shared__ float4 sC[1024];
  const int wq   = blockIdx.x * 4 + (threadIdx.x >> 6);  // query id in [0, B*S)
  const int lane = threadIdx.x & 63;
  const int b    = wq >> 12;
  const float4* Cb = Pts + b * CN;
  float4 pq = (MODE == 0) ? Cb[smp[wq]] : Cb[wq & (CN - 1)];

  const float INF = __uint_as_float(0x7f800000u);
  float d0 = INF, d1 = INF, d2v = INF, d3 = INF;
  int   i0 = 0,   i1 = 0,   i2 = 0,    i3 = 0;

  for (int t0 = 0; t0 < CN; t0 += 1024) {
    for (int j = threadIdx.x; j < 1024; j += 256) sC[j] = Cb[t0 + j];
    __syncthreads();
    #pragma unroll 8
    for (int i = lane; i < 1024; i += 64) {
      float4 cp = sC[i];
      float dot = __fadd_rn(__fadd_rn(__fmul_rn(pq.x, cp.x), __fmul_rn(pq.y, cp.y)),
                            __fmul_rn(pq.z, cp.z));
      float f = __fsub_rn(__fadd_rn(pq.w, cp.w), __fmul_rn(2.0f, dot));
      f = fmaxf(f, 1e-12f);
      int m = t0 + i;
      // branchless stable sorted insert (strict < keeps earlier index on ties)
      bool l3 = f < d3, l2 = f < d2v, l1 = f < d1, l0 = f < d0;
      float nd3 = l2 ? d2v : (l3 ? f : d3);  int ni3 = l2 ? i2 : (l3 ? m : i3);
      float nd2 = l1 ? d1  : (l2 ? f : d2v); int ni2 = l1 ? i1 : (l2 ? m : i2);
      float nd1 = l0 ? d0  : (l1 ? f : d1);  int ni1 = l0 ? i0 : (l1 ? m : i1);
      float nd0 = l0 ? f : d0;               int ni0 = l0 ? m : i0;
      d3 = nd3; i3 = ni3; d2v = nd2; i2 = ni2; d1 = nd1; i1 = ni1; d0 = nd0; i0 = ni0;
    }
    __syncthreads();
  }

  // pack (d2bits, idx) keys and 64-lane butterfly merge of sorted-4 lists
  unsigned long long k0 = ((unsigned long long)__float_as_uint(d0) << 32) | (unsigned)i0;
  unsigned long long k1 = ((unsigned long long)__float_as_uint(d1) << 32) | (unsigned)i1;
  unsigned long long k2 = ((unsigned long long)__float_as_uint(d2v) << 32) | (unsigned)i2;
  unsigned long long k3 = ((unsigned long long)__float_as_uint(d3) << 32) | (unsigned)i3;
  #pragma unroll
  for (int off = 1; off < 64; off <<= 1) {
    unsigned long long b0 = __shfl_xor(k0, off, 64);
    unsigned long long b1 = __shfl_xor(k1, off, 64);
    unsigned long long b2 = __shfl_xor(k2, off, 64);
    unsigned long long b3 = __shfl_xor(k3, off, 64);
    unsigned long long m0 = k0 < b3 ? k0 : b3;
    unsigned long long m1 = k1 < b2 ? k1 : b2;
    unsigned long long m2 = k2 < b1 ? k2 : b1;
    unsigned long long m3 = k3 < b0 ? k3 : b0;
    ce64(m0, m2); ce64(m1, m3); ce64(m0, m1); ce64(m2, m3);
    k0 = m0; k1 = m1; k2 = m2; k3 = m3;
  }
  if (lane == 0) {
    int a0 = (int)(unsigned)k0, a1 = (int)(unsigned)k1;
    int a2 = (int)(unsigned)k2, a3 = (int)(unsigned)k3;
    float e1 = sqrtf(__uint_as_float((unsigned)(k1 >> 32)));
    float e2 = sqrtf(__uint_as_float((unsigned)(k2 >> 32)));
    float e3 = sqrtf(__uint_as_float((unsigned)(k3 >> 32)));
    float4 p1 = Cb[a1], p2 = Cb[a2], p3 = Cb[a3];
    float* tr = trans + wq * cTR + (MODE == 0 ? 0 : 6);
    tr[0] = e1; tr[1] = e2; tr[2] = e3;
    tr[3] = dist_rn(p1, p2); tr[4] = dist_rn(p1, p3); tr[5] = dist_rn(p2, p3);
    int* ao = Aout + wq * 4;
    if (MODE == 0) {
      ao[0] = a0; ao[1] = a1; ao[2] = a2; ao[3] = a3;
    } else {
      const int* sb = smp + b * cS;
      ao[0] = sb[a0]; ao[1] = sb[a1]; ao[2] = sb[a2]; ao[3] = sb[a3];
    }
  }
}

// ---- K4: fused inter-dists + 3-layer MLP; all weights resident in LDS ----
// block = 512 threads, grid = 256 (1 block/CU, LDS ~99 KB), grid-stride over 1024 groups of 8 queries
__global__ __launch_bounds__(512) void mlp_fused_kernel(
    const float* __restrict__ TR, const float4* __restrict__ P,
    const int* __restrict__ AB, const int* __restrict__ AA,
    const float* __restrict__ feat, const int* __restrict__ smp,
    const float* __restrict__ w1, const float* __restrict__ b1,
    const float* __restrict__ g1, const float* __restrict__ be1,
    const float* __restrict__ w2, const float* __restrict__ b2,
    const float* __restrict__ g2, const float* __restrict__ be2,
    const float* __restrict__ w3, const float* __restrict__ b3,
    const float* __restrict__ g3, const float* __restrict__ be3,
    float* __restrict__ out) {
  __shared__ float sw1[28 * 64];
  __shared__ float sw2[64 * 64];
  __shared__ float sw3[128 * 128];
  __shared__ float sb1[64], sg1[64], sbe1[64];
  __shared__ float sb2[64], sg2[64], sbe2[64];
  __shared__ float sb3[128], sg3[128], sbe3[128];
  __shared__ float tin[8 * 28];     // L1 input (28 ch per query)
  __shared__ float sh[8][64];       // L1 output
  __shared__ float sx[8][128];      // L3 input: [0:64)=feat, [64:128)=L2 output

  const int tid = threadIdx.x;
  const float inv = 1.0f / sqrtf(1.0f + 1e-5f);
  for (int i = tid; i < 28 * 64; i += 512) sw1[i] = w1[i];
  for (int i = tid; i < 64 * 64; i += 512) sw2[i] = w2[i];
  for (int i = tid; i < 128 * 128; i += 512) sw3[i] = w3[i];
  if (tid < 64) {
    sb1[tid] = b1[tid]; sg1[tid] = g1[tid] * inv; sbe1[tid] = be1[tid];
    sb2[tid] = b2[tid]; sg2[tid] = g2[tid] * inv; sbe2[tid] = be2[tid];
  } else if (tid < 192) {
    int c = tid - 64;
    sb3[c] = b3[c]; sg3[c] = g3[c] * inv; sbe3[c] = be3[c];
  }
  __syncthreads();

  const int q = tid >> 6;       // query slot 0..7 (wave-uniform)
  const int c = tid & 63;       // channel 0..63

  for (int g = blockIdx.x; g < (cB * cS) / 8; g += gridDim.x) {
    const int q0 = g * 8;
    // ---- stage: feat (all threads), trans ch0-11, inter ch12-27 ----
    {
      int gq = q0 + q, bb = gq >> 12;
      sx[q][c] = feat[((bb << 13) + smp[gq]) * 64 + c];
    }
    if (tid < 128) {
      int qs = tid >> 4, cc = tid & 15;
      if (cc < 12) tin[qs * 28 + cc] = TR[(q0 + qs) * cTR + cc];
    } else if (tid < 256) {
      int u = tid - 128;
      int qs = u >> 4, cc = u & 15;
      int gq = q0 + qs, bb = gq >> 12;
      int ii = AB[gq * 4 + (cc >> 2)];
      int jj = AA[gq * 4 + (cc & 3)];
      const float4* Pb = P + (bb << 13);
      tin[qs * 28 + 12 + cc] = dist_rn(Pb[ii], Pb[jj]);
    }
    __syncthreads();
    // ---- L1: 28 -> 64 ----
    {
      float acc = sb1[c];
      #pragma unroll
      for (int k = 0; k < 28; k++) acc = fmaf(tin[q * 28 + k], sw1[k * 64 + c], acc);
      float x = fmaf(acc, sg1[c], sbe1[c]);
      sh[q][c] = x >= 0.0f ? x : 0.2f * x;
    }
    __syncthreads();
    // ---- L2: 64 -> 64 ----
    {
      float acc = sb2[c];
      #pragma unroll
      for (int k = 0; k < 64; k++) acc = fmaf(sh[q][k], sw2[k * 64 + c], acc);
      float x = fmaf(acc, sg2[c], sbe2[c]);
      sx[q][64 + c] = x >= 0.0f ? x : 0.2f * x;
    }
    __syncthreads();
    // ---- L3: 128 -> 128 (each thread does channels c and c+64) ----
    {
      float a0 = sb3[c], a1 = sb3[c + 64];
      #pragma unroll
      for (int k = 0; k < 128; k++) {
        float xv = sx[q][k];
        a0 = fmaf(xv, sw3[k * 128 + c], a0);
        a1 = fmaf(xv, sw3[k * 128 + 64 + c], a1);
      }
      float x0 = fmaf(a0, sg3[c], sbe3[c]);
      float x1 = fmaf(a1, sg3[c + 64], sbe3[c + 64]);
      x0 = x0 >= 0.0f ? x0 : 0.2f * x0;
      x1 = x1 >= 0.0f ? x1 : 0.2f * x1;
      out[(q0 + q) * 128 + c] = x0;
      out[(q0 + q) * 128 + 64 + c] = x1;
    }
    __syncthreads();
  }
}

extern "C" void kernel_launch(void* const* d_in, const int* in_sizes, int n_in,
                              void* d_out, int out_size, void* d_ws, size_t ws_size,
                              hipStream_t stream) {
  const float* xyz  = (const float*)d_in[0];
  const float* feat = (const float*)d_in[1];
  const int*   smp  = (const int*)d_in[2];
  const float* w1   = (const float*)d_in[3];
  const float* b1   = (const float*)d_in[4];
  const float* g1   = (const float*)d_in[5];
  const float* be1  = (const float*)d_in[6];
  const float* w2   = (const float*)d_in[7];
  const float* b2   = (const float*)d_in[8];
  const float* g2   = (const float*)d_in[9];
  const float* be2  = (const float*)d_in[10];
  const float* w3   = (const float*)d_in[11];
  const float* b3   = (const float*)d_in[12];
  const float* g3   = (const float*)d_in[13];
  const float* be3  = (const float*)d_in[14];
  float* out = (float*)d_out;

  char* ws = (char*)d_ws;
  float4* P  = (float4*)(ws);                     // B*N*16    = 262144 B
  float4* SP = (float4*)(ws + 262144);            // B*S*16    = 131072 B
  float*  TR = (float*)(ws + 393216);             // B*S*12*4  = 393216 B
  int*    AB = (int*)(ws + 786432);               // B*S*4*4   = 131072 B
  int*    AA = (int*)(ws + 917504);               // B*S*4*4   = 131072 B

  pack_kernel<<<96, 256, 0, stream>>>(xyz, smp, P, SP, out);
  knn_kernel<0, cN><<<(cB * cS) / 4, 256, 0, stream>>>(P, smp, TR, AB);
  knn_kernel<1, cS><<<(cB * cS) / 4, 256, 0, stream>>>(SP, smp, TR, AA);
  mlp_fused_kernel<<<256, 512, 0, stream>>>(TR, P, AB, AA, feat, smp,
                                            w1, b1, g1, be1, w2, b2, g2, be2,
                                            w3, b3, g3, be3, out + cB * cS * 3);
}

// Round 4
// 192.524 us; speedup vs baseline: 1.1658x; 1.0147x over previous
//
#include <hip/hip_runtime.h>
#include <math.h>

// Problem constants (match reference)
constexpr int cB = 2, cN = 8192, cS = 4096;
constexpr int cTR = 12;    // stored trans channels (0-5 before, 6-11 after)
constexpr int SCR = 20;    // padded scratch row stride (floats): 16B-aligned, breaks 32-bank stride

// ---- distance helpers: EXACTLY mirror reference arithmetic ----
__device__ __forceinline__ float d2clamp_rn(const float4 a, const float4 b) {
  float dot = __fadd_rn(__fadd_rn(__fmul_rn(a.x, b.x), __fmul_rn(a.y, b.y)), __fmul_rn(a.z, b.z));
  float d2  = __fsub_rn(__fadd_rn(a.w, b.w), __fmul_rn(2.0f, dot));
  return fmaxf(d2, 1e-12f);
}
__device__ __forceinline__ float dist_rn(const float4 a, const float4 b) {
  return sqrtf(d2clamp_rn(a, b));
}
__device__ __forceinline__ void ce64(unsigned long long& a, unsigned long long& b) {
  unsigned long long lo = a < b ? a : b;
  unsigned long long hi = a < b ? b : a;
  a = lo; b = hi;
}

// ---- K1: pack P[b][n] = (x,y,z,sq); SP[b][s]; emit sampled_xyz ----
__global__ __launch_bounds__(256) void pack_kernel(const float* __restrict__ xyz,
                                                   const int* __restrict__ smp,
                                                   float4* __restrict__ P,
                                                   float4* __restrict__ SP,
                                                   float* __restrict__ oxyz) {
  int t = blockIdx.x * 256 + threadIdx.x;
  if (t < cB * cN) {
    const float* p = xyz + t * 3;
    float x = p[0], y = p[1], z = p[2];
    float sq = __fadd_rn(__fadd_rn(__fmul_rn(x, x), __fmul_rn(y, y)), __fmul_rn(z, z));
    P[t] = make_float4(x, y, z, sq);
  } else if (t < cB * cN + cB * cS) {
    int j = t - cB * cN;
    int b = j >> 12;
    int idx = smp[j];
    const float* p = xyz + (b * cN + idx) * 3;
    float x = p[0], y = p[1], z = p[2];
    float sq = __fadd_rn(__fadd_rn(__fmul_rn(x, x), __fmul_rn(y, y)), __fmul_rn(z, z));
    SP[j] = make_float4(x, y, z, sq);
    oxyz[j * 3 + 0] = x; oxyz[j * 3 + 1] = y; oxyz[j * 3 + 2] = z;
  }
}

// ---- K2: combined 4-NN over 4096 blocks: [0,2048) mode0 (all-points), [2048,4096) mode1 (sampled) ----
// Each mode covers all B*S = 8192 queries (4 query-waves per block).
// Gate: tau = 4th-smallest distance value seen wave-wide (refreshed per tile).
// Safe: any candidate rejected by (f > tau) has >=4 strictly-better keys already held.
__global__ __launch_bounds__(256) void knn_kernel(const float4* __restrict__ P,
                                                  const float4* __restrict__ SP,
                                                  const int* __restrict__ smp,
                                                  float* __restrict__ trans,
                                                  int* __restrict__ AB,
                                                  int* __restrict__ AA) {
  __shared__ alignas(16) float4 sC[1024];
  const int mode = (blockIdx.x >= 2048) ? 1 : 0;
  const int wq   = (blockIdx.x - (mode ? 2048 : 0)) * 4 + (threadIdx.x >> 6);  // [0, 8192)
  const int lane = threadIdx.x & 63;
  const int b    = wq >> 12;
  const int CN   = mode ? cS : cN;
  const float4* Cb = (mode ? SP : P) + b * CN;
  float4 pq = mode ? Cb[wq & (cS - 1)] : Cb[smp[wq]];

  const unsigned long long K_EMPTY = 0x7F800000FFFFFFFFull;  // (+inf, idx=~0)
  unsigned long long k0 = K_EMPTY, k1 = K_EMPTY, k2 = K_EMPTY, k3 = K_EMPTY;
  float tau = __uint_as_float(0x7f800000u);  // +inf

  for (int t0 = 0; t0 < CN; t0 += 1024) {
    for (int j = threadIdx.x; j < 1024; j += 256) sC[j] = Cb[t0 + j];
    __syncthreads();
    #pragma unroll
    for (int u = 0; u < 16; u++) {
      float4 cp = sC[u * 64 + lane];
      float dot = __fadd_rn(__fadd_rn(__fmul_rn(pq.x, cp.x), __fmul_rn(pq.y, cp.y)),
                            __fmul_rn(pq.z, cp.z));
      float f = __fsub_rn(__fadd_rn(pq.w, cp.w), __fmul_rn(2.0f, dot));
      if (f <= tau) {               // rare after tile 0
        float fc = fmaxf(f, 1e-12f);
        unsigned long long key =
            ((unsigned long long)__float_as_uint(fc) << 32) | (unsigned)(t0 + u * 64 + lane);
        if (key < k3) { k3 = key; ce64(k2, k3); ce64(k1, k2); ce64(k0, k1); }
      }
    }
    // refresh tau: exact 4th-smallest value across the wave (value multiset — safe)
    int tt = t0 >> 10;
    if (tt < 4 || (tt & 1)) {
      float a0 = __uint_as_float((unsigned)(k0 >> 32));
      float a1 = __uint_as_float((unsigned)(k1 >> 32));
      float a2 = __uint_as_float((unsigned)(k2 >> 32));
      float a3 = __uint_as_float((unsigned)(k3 >> 32));
      #pragma unroll
      for (int off = 1; off < 64; off <<= 1) {
        float q0 = __shfl_xor(a0, off, 64);
        float q1 = __shfl_xor(a1, off, 64);
        float q2 = __shfl_xor(a2, off, 64);
        float q3 = __shfl_xor(a3, off, 64);
        float n0 = fminf(a0, q3), n1 = fminf(a1, q2), n2 = fminf(a2, q1), n3 = fminf(a3, q0);
        float t;
        t = fminf(n0, n2); n2 = fmaxf(n0, n2); n0 = t;
        t = fminf(n1, n3); n3 = fmaxf(n1, n3); n1 = t;
        t = fminf(n0, n1); n1 = fmaxf(n0, n1); n0 = t;
        t = fminf(n2, n3); n3 = fmaxf(n2, n3); n2 = t;
        a0 = n0; a1 = n1; a2 = n2; a3 = n3;
      }
      tau = a3;
    }
    __syncthreads();
  }

  // final exact u64 butterfly merge (per-lane lists sorted & duplicate-free)
  #pragma unroll
  for (int off = 1; off < 64; off <<= 1) {
    unsigned long long b0 = __shfl_xor(k0, off, 64);
    unsigned long long b1 = __shfl_xor(k1, off, 64);
    unsigned long long b2 = __shfl_xor(k2, off, 64);
    unsigned long long b3 = __shfl_xor(k3, off, 64);
    unsigned long long m0 = k0 < b3 ? k0 : b3;
    unsigned long long m1 = k1 < b2 ? k1 : b2;
    unsigned long long m2 = k2 < b1 ? k2 : b1;
    unsigned long long m3 = k3 < b0 ? k3 : b0;
    ce64(m0, m2); ce64(m1, m3); ce64(m0, m1); ce64(m2, m3);
    k0 = m0; k1 = m1; k2 = m2; k3 = m3;
  }
  if (lane == 0) {
    int a0 = (int)(unsigned)k0, a1 = (int)(unsigned)k1;
    int a2 = (int)(unsigned)k2, a3 = (int)(unsigned)k3;
    float e1 = sqrtf(__uint_as_float((unsigned)(k1 >> 32)));
    float e2 = sqrtf(__uint_as_float((unsigned)(k2 >> 32)));
    float e3 = sqrtf(__uint_as_float((unsigned)(k3 >> 32)));
    float4 p1 = Cb[a1], p2 = Cb[a2], p3 = Cb[a3];
    float* tr = trans + wq * cTR + (mode ? 6 : 0);
    tr[0] = e1; tr[1] = e2; tr[2] = e3;
    tr[3] = dist_rn(p1, p2); tr[4] = dist_rn(p1, p3); tr[5] = dist_rn(p2, p3);
    if (mode == 0) {
      int* ao = AB + wq * 4;
      ao[0] = a0; ao[1] = a1; ao[2] = a2; ao[3] = a3;
    } else {
      const int* sb = smp + b * cS;
      int* ao = AA + wq * 4;
      ao[0] = sb[a0]; ao[1] = sb[a1]; ao[2] = sb[a2]; ao[3] = sb[a3];
    }
  }
}

// 16-row FMA helper: activations via broadcast b128 reads
__device__ __forceinline__ void fma16(float acc[16], const float* a, float w) {
  float4 x0 = *(const float4*)(a);
  float4 x1 = *(const float4*)(a + 4);
  float4 x2 = *(const float4*)(a + 8);
  float4 x3 = *(const float4*)(a + 12);
  acc[0]  = fmaf(x0.x, w, acc[0]);  acc[1]  = fmaf(x0.y, w, acc[1]);
  acc[2]  = fmaf(x0.z, w, acc[2]);  acc[3]  = fmaf(x0.w, w, acc[3]);
  acc[4]  = fmaf(x1.x, w, acc[4]);  acc[5]  = fmaf(x1.y, w, acc[5]);
  acc[6]  = fmaf(x1.z, w, acc[6]);  acc[7]  = fmaf(x1.w, w, acc[7]);
  acc[8]  = fmaf(x2.x, w, acc[8]);  acc[9]  = fmaf(x2.y, w, acc[9]);
  acc[10] = fmaf(x2.z, w, acc[10]); acc[11] = fmaf(x2.w, w, acc[11]);
  acc[12] = fmaf(x3.x, w, acc[12]); acc[13] = fmaf(x3.y, w, acc[13]);
  acc[14] = fmaf(x3.z, w, acc[14]); acc[15] = fmaf(x3.w, w, acc[15]);
}

// ---- K3: fused inter-dists + 3-layer MLP; wave = 16 rows, lane = channel ----
// Weight reads amortized over 16 rows; activations transposed in LDS, read as broadcast b128.
__global__ __launch_bounds__(128) void mlp_kernel(
    const float* __restrict__ TR, const float4* __restrict__ P,
    const int* __restrict__ AB, const int* __restrict__ AA,
    const float* __restrict__ feat, const int* __restrict__ smp,
    const float* __restrict__ w1, const float* __restrict__ b1,
    const float* __restrict__ g1, const float* __restrict__ be1,
    const float* __restrict__ w2, const float* __restrict__ b2,
    const float* __restrict__ g2, const float* __restrict__ be2,
    const float* __restrict__ w3, const float* __restrict__ b3,
    const float* __restrict__ g3, const float* __restrict__ be3,
    float* __restrict__ out) {
  __shared__ alignas(16) float sw1[28 * 64];
  __shared__ alignas(16) float sw2[64 * 64];
  __shared__ alignas(16) float sw3[128 * 128];
  __shared__ alignas(16) float scr[2][(28 + 64 + 128) * SCR];   // per-wave: tinT | act1T | act2T

  const int tid = threadIdx.x;
  for (int i = tid; i < 28 * 64 / 4; i += 128) ((float4*)sw1)[i] = ((const float4*)w1)[i];
  for (int i = tid; i < 64 * 64 / 4; i += 128) ((float4*)sw2)[i] = ((const float4*)w2)[i];
  for (int i = tid; i < 128 * 128 / 4; i += 128) ((float4*)sw3)[i] = ((const float4*)w3)[i];

  const int wv = tid >> 6, lane = tid & 63;
  const int grp = blockIdx.x * 2 + wv;          // 0..511
  const int r0 = grp * 16;                      // rows r0..r0+15 (same batch: 16 | 4096)
  const int b = r0 >> 12;
  const float inv = 1.0f / sqrtf(1.0f + 1e-5f);
  float* tinT  = scr[wv];
  float* act1T = scr[wv] + 28 * SCR;
  float* act2T = scr[wv] + (28 + 64) * SCR;     // rows 0..63 = feat, 64..127 = L2 out

  float pb1 = b1[lane], pg1 = g1[lane] * inv, pe1 = be1[lane];
  float pb2 = b2[lane], pg2 = g2[lane] * inv, pe2 = be2[lane];
  float pb3a = b3[lane],      pg3a = g3[lane] * inv,      pe3a = be3[lane];
  float pb3b = b3[lane + 64], pg3b = g3[lane + 64] * inv, pe3b = be3[lane + 64];

  // stage feat -> act2T rows 0..63 (lane = feature channel)
  {
    const float* fb = feat + (size_t)b * cN * 64;
    #pragma unroll 4
    for (int r = 0; r < 16; r++) {
      int row = smp[r0 + r];
      act2T[lane * SCR + r] = fb[row * 64 + lane];
    }
  }
  // stage tinT: ch 0..11 from TR, ch 12..27 = inter dists (7*64 = 448 = 28ch*16r items)
  {
    const float4* Pb = P + b * cN;
    #pragma unroll
    for (int t = 0; t < 7; t++) {
      int idx = t * 64 + lane;
      int r = idx & 15, ch = idx >> 4;
      float v;
      if (ch < 12) {
        v = TR[(r0 + r) * cTR + ch];
      } else {
        int cc = ch - 12;
        int gi = AB[(r0 + r) * 4 + (cc >> 2)];
        int gj = AA[(r0 + r) * 4 + (cc & 3)];
        v = dist_rn(Pb[gi], Pb[gj]);
      }
      tinT[ch * SCR + r] = v;
    }
  }
  __syncthreads();

  float acc[16];
  // ---- L1: 28 -> 64 ----
  #pragma unroll
  for (int r = 0; r < 16; r++) acc[r] = pb1;
  for (int k = 0; k < 28; k++) fma16(acc, tinT + k * SCR, sw1[k * 64 + lane]);
  #pragma unroll
  for (int r = 0; r < 16; r++) {
    float x = fmaf(acc[r], pg1, pe1);
    act1T[lane * SCR + r] = x >= 0.0f ? x : 0.2f * x;
  }
  __syncthreads();
  // ---- L2: 64 -> 64 ----
  #pragma unroll
  for (int r = 0; r < 16; r++) acc[r] = pb2;
  for (int k = 0; k < 64; k++) fma16(acc, act1T + k * SCR, sw2[k * 64 + lane]);
  #pragma unroll
  for (int r = 0; r < 16; r++) {
    float x = fmaf(acc[r], pg2, pe2);
    act2T[(64 + lane) * SCR + r] = x >= 0.0f ? x : 0.2f * x;
  }
  __syncthreads();
  // ---- L3: 128 -> 128 (lane covers channels lane and lane+64) ----
  float accA[16], accB[16];
  #pragma unroll
  for (int r = 0; r < 16; r++) { accA[r] = pb3a; accB[r] = pb3b; }
  for (int k = 0; k < 128; k++) {
    const float* a = act2T + k * SCR;
    float wA = sw3[k * 128 + lane];
    float wB = sw3[k * 128 + 64 + lane];
    fma16(accA, a, wA);
    fma16(accB, a, wB);
  }
  #pragma unroll
  for (int r = 0; r < 16; r++) {
    float xA = fmaf(accA[r], pg3a, pe3a);
    float xB = fmaf(accB[r], pg3b, pe3b);
    xA = xA >= 0.0f ? xA : 0.2f * xA;
    xB = xB >= 0.0f ? xB : 0.2f * xB;
    out[(r0 + r) * 128 + lane] = xA;
    out[(r0 + r) * 128 + 64 + lane] = xB;
  }
}

extern "C" void kernel_launch(void* const* d_in, const int* in_sizes, int n_in,
                              void* d_out, int out_size, void* d_ws, size_t ws_size,
                              hipStream_t stream) {
  const float* xyz  = (const float*)d_in[0];
  const float* feat = (const float*)d_in[1];
  const int*   smp  = (const int*)d_in[2];
  const float* w1   = (const float*)d_in[3];
  const float* b1   = (const float*)d_in[4];
  const float* g1   = (const float*)d_in[5];
  const float* be1  = (const float*)d_in[6];
  const float* w2   = (const float*)d_in[7];
  const float* b2   = (const float*)d_in[8];
  const float* g2   = (const float*)d_in[9];
  const float* be2  = (const float*)d_in[10];
  const float* w3   = (const float*)d_in[11];
  const float* b3   = (const float*)d_in[12];
  const float* g3   = (const float*)d_in[13];
  const float* be3  = (const float*)d_in[14];
  float* out = (float*)d_out;

  char* ws = (char*)d_ws;
  float4* P  = (float4*)(ws);                     // B*N*16    = 262144 B
  float4* SP = (float4*)(ws + 262144);            // B*S*16    = 131072 B
  float*  TR = (float*)(ws + 393216);             // B*S*12*4  = 393216 B
  int*    AB = (int*)(ws + 786432);               // B*S*4*4   = 131072 B
  int*    AA = (int*)(ws + 917504);               // B*S*4*4   = 131072 B

  pack_kernel<<<96, 256, 0, stream>>>(xyz, smp, P, SP, out);
  knn_kernel<<<4096, 256, 0, stream>>>(P, SP, smp, TR, AB, AA);
  mlp_kernel<<<256, 128, 0, stream>>>(TR, P, AB, AA, feat, smp,
                                      w1, b1, g1, be1, w2, b2, g2, be2,
                                      w3, b3, g3, be3, out + cB * cS * 3);
}

// Round 5
// 173.853 us; speedup vs baseline: 1.2910x; 1.1074x over previous
//
#include <hip/hip_runtime.h>
#include <math.h>

// Problem constants (match reference)
constexpr int cB = 2, cN = 8192, cS = 4096;
constexpr int cTR = 12;    // stored trans channels (0-5 before, 6-11 after)
constexpr int SCR = 12;    // MLP scratch row stride (8 rows + 4 pad; 16B-aligned)

// ---- distance helpers: EXACTLY mirror reference arithmetic ----
// ref: sq = (x*x + y*y) + z*z ; d2 = (sq_i + sq_j) - 2*dot ; d = sqrt(max(d2,1e-12))
__device__ __forceinline__ float d2raw_rn(const float4 a, const float4 b) {
  float dot = __fadd_rn(__fadd_rn(__fmul_rn(a.x, b.x), __fmul_rn(a.y, b.y)), __fmul_rn(a.z, b.z));
  return __fsub_rn(__fadd_rn(a.w, b.w), __fmul_rn(2.0f, dot));
}
__device__ __forceinline__ float dist_rn(const float4 a, const float4 b) {
  return sqrtf(fmaxf(d2raw_rn(a, b), 1e-12f));
}
__device__ __forceinline__ void ce64(unsigned long long& a, unsigned long long& b) {
  unsigned long long lo = a < b ? a : b;
  unsigned long long hi = a < b ? b : a;
  a = lo; b = hi;
}

// ---- K1: pack P[b][n] = (x,y,z,sq); SP[b][s]; emit sampled_xyz ----
__global__ __launch_bounds__(256) void pack_kernel(const float* __restrict__ xyz,
                                                   const int* __restrict__ smp,
                                                   float4* __restrict__ P,
                                                   float4* __restrict__ SP,
                                                   float* __restrict__ oxyz) {
  int t = blockIdx.x * 256 + threadIdx.x;
  if (t < cB * cN) {
    const float* p = xyz + t * 3;
    float x = p[0], y = p[1], z = p[2];
    float sq = __fadd_rn(__fadd_rn(__fmul_rn(x, x), __fmul_rn(y, y)), __fmul_rn(z, z));
    P[t] = make_float4(x, y, z, sq);
  } else if (t < cB * cN + cB * cS) {
    int j = t - cB * cN;
    int b = j >> 12;
    int idx = smp[j];
    const float* p = xyz + (b * cN + idx) * 3;
    float x = p[0], y = p[1], z = p[2];
    float sq = __fadd_rn(__fadd_rn(__fmul_rn(x, x), __fmul_rn(y, y)), __fmul_rn(z, z));
    SP[j] = make_float4(x, y, z, sq);
    oxyz[j * 3 + 0] = x; oxyz[j * 3 + 1] = y; oxyz[j * 3 + 2] = z;
  }
}

// ---- K2: two-pass 4-NN. 1024 blocks: [0,512) mode0 (all-point cands), [512,1024) mode1 (sampled) ----
// Block = 4 waves x 4 queries = 16 queries. Pass A: per-lane min only. tau = 4th-smallest of the
// 64 lane-minima (safe upper bound on d(4): any lane-min is one of d(1..3) or >= d(4), so at most 3
// lane-minima lie below d(4); and the 4 smallest lane-minima are real candidates <= tau).
// Pass B: re-scan, push survivors (fc <= tau) to LDS, exact u64 (d2bits,idx) butterfly select.
__global__ __launch_bounds__(256) void knn_kernel(const float4* __restrict__ P,
                                                  const float4* __restrict__ SP,
                                                  const int* __restrict__ smp,
                                                  float* __restrict__ trans,
                                                  int* __restrict__ AB,
                                                  int* __restrict__ AA) {
  __shared__ alignas(16) float4 sC[1024];
  __shared__ unsigned long long sBuf[16][64];
  __shared__ int sCnt[16];

  const int mode = (blockIdx.x >= 512) ? 1 : 0;
  const int blk  = blockIdx.x - (mode ? 512 : 0);
  const int wv   = threadIdx.x >> 6, lane = threadIdx.x & 63;
  const int q0   = blk * 16 + wv * 4;           // first of this wave's 4 queries, [0, 8192)
  const int b    = q0 >> 12;                    // all 4 in same batch (16-aligned groups)
  const int CN   = mode ? cS : cN;
  const float4* Cb = (mode ? SP : P) + b * CN;

  float4 pq[4];
  #pragma unroll
  for (int qi = 0; qi < 4; qi++)
    pq[qi] = mode ? Cb[(q0 + qi) & (cS - 1)] : Cb[smp[q0 + qi]];

  const float INF = __uint_as_float(0x7f800000u);
  float mn0 = INF, mn1 = INF, mn2 = INF, mn3 = INF;

  // ---- Pass A: per-lane min per query ----
  for (int t0 = 0; t0 < CN; t0 += 1024) {
    for (int j = threadIdx.x; j < 1024; j += 256) sC[j] = Cb[t0 + j];
    __syncthreads();
    #pragma unroll 4
    for (int u = 0; u < 16; u++) {
      float4 cp = sC[u * 64 + lane];
      mn0 = fminf(mn0, d2raw_rn(pq[0], cp));
      mn1 = fminf(mn1, d2raw_rn(pq[1], cp));
      mn2 = fminf(mn2, d2raw_rn(pq[2], cp));
      mn3 = fminf(mn3, d2raw_rn(pq[3], cp));
    }
    __syncthreads();
  }

  // tau[qi] = 4th-smallest of 64 lane minima (clamped like the reference)
  float tau[4];
  float mns[4] = {mn0, mn1, mn2, mn3};
  #pragma unroll
  for (int qi = 0; qi < 4; qi++) {
    float a0 = mns[qi], a1 = INF, a2 = INF, a3 = INF;
    #pragma unroll
    for (int off = 1; off < 64; off <<= 1) {
      float s0 = __shfl_xor(a0, off, 64);
      float s1 = __shfl_xor(a1, off, 64);
      float s2 = __shfl_xor(a2, off, 64);
      float s3 = __shfl_xor(a3, off, 64);
      float n0 = fminf(a0, s3), n1 = fminf(a1, s2), n2 = fminf(a2, s1), n3 = fminf(a3, s0);
      float t;
      t = fminf(n0, n2); n2 = fmaxf(n0, n2); n0 = t;
      t = fminf(n1, n3); n3 = fmaxf(n1, n3); n1 = t;
      t = fminf(n0, n1); n1 = fmaxf(n0, n1); n0 = t;
      t = fminf(n2, n3); n3 = fmaxf(n2, n3); n2 = t;
      a0 = n0; a1 = n1; a2 = n2; a3 = n3;
    }
    tau[qi] = fmaxf(a3, 1e-12f);
  }

  // ---- Pass B: collect survivors ----
  if (threadIdx.x < 16) sCnt[threadIdx.x] = 0;
  for (int t0 = 0; t0 < CN; t0 += 1024) {
    for (int j = threadIdx.x; j < 1024; j += 256) sC[j] = Cb[t0 + j];
    __syncthreads();   // first barrier also publishes sCnt=0
    #pragma unroll 4
    for (int u = 0; u < 16; u++) {
      float4 cp = sC[u * 64 + lane];
      int m = t0 + u * 64 + lane;
      #pragma unroll
      for (int qi = 0; qi < 4; qi++) {
        float fc = fmaxf(d2raw_rn(pq[qi], cp), 1e-12f);
        if (fc <= tau[qi]) {          // rare
          int slot = atomicAdd(&sCnt[wv * 4 + qi], 1);
          if (slot < 64)
            sBuf[wv * 4 + qi][slot] =
                ((unsigned long long)__float_as_uint(fc) << 32) | (unsigned)m;
        }
      }
    }
    __syncthreads();
  }

  // ---- exact top-4 per query: u64 butterfly over survivors ----
  const unsigned long long K_EMPTY = 0x7F800000FFFFFFFFull;
  #pragma unroll
  for (int qi = 0; qi < 4; qi++) {
    int qidx = wv * 4 + qi;
    int cnt = sCnt[qidx]; cnt = cnt > 64 ? 64 : cnt;
    unsigned long long k0 = (lane < cnt) ? sBuf[qidx][lane] : K_EMPTY;
    unsigned long long k1 = K_EMPTY, k2 = K_EMPTY, k3 = K_EMPTY;
    #pragma unroll
    for (int off = 1; off < 64; off <<= 1) {
      unsigned long long b0 = __shfl_xor(k0, off, 64);
      unsigned long long b1 = __shfl_xor(k1, off, 64);
      unsigned long long b2 = __shfl_xor(k2, off, 64);
      unsigned long long b3 = __shfl_xor(k3, off, 64);
      unsigned long long m0 = k0 < b3 ? k0 : b3;
      unsigned long long m1 = k1 < b2 ? k1 : b2;
      unsigned long long m2 = k2 < b1 ? k2 : b1;
      unsigned long long m3 = k3 < b0 ? k3 : b0;
      ce64(m0, m2); ce64(m1, m3); ce64(m0, m1); ce64(m2, m3);
      k0 = m0; k1 = m1; k2 = m2; k3 = m3;
    }
    if (lane == 0) {
      int wq = q0 + qi;
      int a0 = (int)(unsigned)k0, a1 = (int)(unsigned)k1;
      int a2 = (int)(unsigned)k2, a3 = (int)(unsigned)k3;
      float e1 = sqrtf(__uint_as_float((unsigned)(k1 >> 32)));
      float e2 = sqrtf(__uint_as_float((unsigned)(k2 >> 32)));
      float e3 = sqrtf(__uint_as_float((unsigned)(k3 >> 32)));
      float4 p1 = Cb[a1], p2 = Cb[a2], p3 = Cb[a3];
      float* tr = trans + wq * cTR + (mode ? 6 : 0);
      tr[0] = e1; tr[1] = e2; tr[2] = e3;
      tr[3] = dist_rn(p1, p2); tr[4] = dist_rn(p1, p3); tr[5] = dist_rn(p2, p3);
      if (mode == 0) {
        int* ao = AB + wq * 4;
        ao[0] = a0; ao[1] = a1; ao[2] = a2; ao[3] = a3;
      } else {
        const int* sb = smp + b * cS;
        int* ao = AA + wq * 4;
        ao[0] = sb[a0]; ao[1] = sb[a1]; ao[2] = sb[a2]; ao[3] = sb[a3];
      }
    }
  }
}

// 8-row FMA helper: activations via broadcast b128 reads (conflict-free)
__device__ __forceinline__ void fma8(float acc[8], const float* a, float w) {
  float4 x0 = *(const float4*)(a);
  float4 x1 = *(const float4*)(a + 4);
  acc[0] = fmaf(x0.x, w, acc[0]); acc[1] = fmaf(x0.y, w, acc[1]);
  acc[2] = fmaf(x0.z, w, acc[2]); acc[3] = fmaf(x0.w, w, acc[3]);
  acc[4] = fmaf(x1.x, w, acc[4]); acc[5] = fmaf(x1.y, w, acc[5]);
  acc[6] = fmaf(x1.z, w, acc[6]); acc[7] = fmaf(x1.w, w, acc[7]);
}

// ---- K3: fused inter-dists + 3-layer MLP; 4 waves x 8 rows per block, lane = channel ----
__global__ __launch_bounds__(256) void mlp_kernel(
    const float* __restrict__ TR, const float4* __restrict__ P,
    const int* __restrict__ AB, const int* __restrict__ AA,
    const float* __restrict__ feat, const int* __restrict__ smp,
    const float* __restrict__ w1, const float* __restrict__ b1,
    const float* __restrict__ g1, const float* __restrict__ be1,
    const float* __restrict__ w2, const float* __restrict__ b2,
    const float* __restrict__ g2, const float* __restrict__ be2,
    const float* __restrict__ w3, const float* __restrict__ b3,
    const float* __restrict__ g3, const float* __restrict__ be3,
    float* __restrict__ out) {
  __shared__ alignas(16) float sw1[28 * 64];
  __shared__ alignas(16) float sw2[64 * 64];
  __shared__ alignas(16) float sw3[128 * 128];
  __shared__ alignas(16) float scr[4][(28 + 64 + 128) * SCR];

  const int tid = threadIdx.x;
  for (int i = tid; i < 28 * 64 / 4; i += 256) ((float4*)sw1)[i] = ((const float4*)w1)[i];
  for (int i = tid; i < 64 * 64 / 4; i += 256) ((float4*)sw2)[i] = ((const float4*)w2)[i];
  for (int i = tid; i < 128 * 128 / 4; i += 256) ((float4*)sw3)[i] = ((const float4*)w3)[i];

  const int wv = tid >> 6, lane = tid & 63;
  const int grp = blockIdx.x * 4 + wv;          // 0..1023
  const int r0 = grp * 8;                       // rows r0..r0+7 (same batch: 8 | 4096)
  const int b = r0 >> 12;
  const float inv = 1.0f / sqrtf(1.0f + 1e-5f);
  float* tinT  = scr[wv];
  float* act1T = scr[wv] + 28 * SCR;
  float* act2T = scr[wv] + (28 + 64) * SCR;     // ch 0..63 = feat, 64..127 = L2 out

  float pb1 = b1[lane], pg1 = g1[lane] * inv, pe1 = be1[lane];
  float pb2 = b2[lane], pg2 = g2[lane] * inv, pe2 = be2[lane];
  float pb3a = b3[lane],      pg3a = g3[lane] * inv,      pe3a = be3[lane];
  float pb3b = b3[lane + 64], pg3b = g3[lane + 64] * inv, pe3b = be3[lane + 64];

  // stage feat -> act2T ch 0..63 (lane = feature channel)
  {
    const float* fb = feat + (size_t)b * cN * 64;
    #pragma unroll
    for (int r = 0; r < 8; r++) {
      int row = smp[r0 + r];
      act2T[lane * SCR + r] = fb[row * 64 + lane];
    }
  }
  // stage tinT: ch 0..11 from TR, ch 12..27 = inter dists (28ch*8r = 224 items)
  {
    const float4* Pb = P + b * cN;
    #pragma unroll
    for (int t = 0; t < 4; t++) {
      int idx = t * 64 + lane;
      if (idx < 224) {
        int r = idx & 7, ch = idx >> 3;
        float v;
        if (ch < 12) {
          v = TR[(r0 + r) * cTR + ch];
        } else {
          int cc = ch - 12;
          int gi = AB[(r0 + r) * 4 + (cc >> 2)];
          int gj = AA[(r0 + r) * 4 + (cc & 3)];
          v = dist_rn(Pb[gi], Pb[gj]);
        }
        tinT[ch * SCR + r] = v;
      }
    }
  }
  __syncthreads();

  float acc[8];
  // ---- L1: 28 -> 64 ----
  #pragma unroll
  for (int r = 0; r < 8; r++) acc[r] = pb1;
  for (int k = 0; k < 28; k++) fma8(acc, tinT + k * SCR, sw1[k * 64 + lane]);
  #pragma unroll
  for (int r = 0; r < 8; r++) {
    float x = fmaf(acc[r], pg1, pe1);
    act1T[lane * SCR + r] = x >= 0.0f ? x : 0.2f * x;
  }
  __syncthreads();
  // ---- L2: 64 -> 64 ----
  #pragma unroll
  for (int r = 0; r < 8; r++) acc[r] = pb2;
  for (int k = 0; k < 64; k++) fma8(acc, act1T + k * SCR, sw2[k * 64 + lane]);
  #pragma unroll
  for (int r = 0; r < 8; r++) {
    float x = fmaf(acc[r], pg2, pe2);
    act2T[(64 + lane) * SCR + r] = x >= 0.0f ? x : 0.2f * x;
  }
  __syncthreads();
  // ---- L3: 128 -> 128 (lane covers channels lane and lane+64) ----
  float accA[8], accB[8];
  #pragma unroll
  for (int r = 0; r < 8; r++) { accA[r] = pb3a; accB[r] = pb3b; }
  for (int k = 0; k < 128; k++) {
    const float* a = act2T + k * SCR;
    fma8(accA, a, sw3[k * 128 + lane]);
    fma8(accB, a, sw3[k * 128 + 64 + lane]);
  }
  #pragma unroll
  for (int r = 0; r < 8; r++) {
    float xA = fmaf(accA[r], pg3a, pe3a);
    float xB = fmaf(accB[r], pg3b, pe3b);
    xA = xA >= 0.0f ? xA : 0.2f * xA;
    xB = xB >= 0.0f ? xB : 0.2f * xB;
    out[(r0 + r) * 128 + lane] = xA;
    out[(r0 + r) * 128 + 64 + lane] = xB;
  }
}

extern "C" void kernel_launch(void* const* d_in, const int* in_sizes, int n_in,
                              void* d_out, int out_size, void* d_ws, size_t ws_size,
                              hipStream_t stream) {
  const float* xyz  = (const float*)d_in[0];
  const float* feat = (const float*)d_in[1];
  const int*   smp  = (const int*)d_in[2];
  const float* w1   = (const float*)d_in[3];
  const float* b1   = (const float*)d_in[4];
  const float* g1   = (const float*)d_in[5];
  const float* be1  = (const float*)d_in[6];
  const float* w2   = (const float*)d_in[7];
  const float* b2   = (const float*)d_in[8];
  const float* g2   = (const float*)d_in[9];
  const float* be2  = (const float*)d_in[10];
  const float* w3   = (const float*)d_in[11];
  const float* b3   = (const float*)d_in[12];
  const float* g3   = (const float*)d_in[13];
  const float* be3  = (const float*)d_in[14];
  float* out = (float*)d_out;

  char* ws = (char*)d_ws;
  float4* P  = (float4*)(ws);                     // B*N*16    = 262144 B
  float4* SP = (float4*)(ws + 262144);            // B*S*16    = 131072 B
  float*  TR = (float*)(ws + 393216);             // B*S*12*4  = 393216 B
  int*    AB = (int*)(ws + 786432);               // B*S*4*4   = 131072 B
  int*    AA = (int*)(ws + 917504);               // B*S*4*4   = 131072 B

  pack_kernel<<<96, 256, 0, stream>>>(xyz, smp, P, SP, out);
  knn_kernel<<<1024, 256, 0, stream>>>(P, SP, smp, TR, AB, AA);
  mlp_kernel<<<256, 256, 0, stream>>>(TR, P, AB, AA, feat, smp,
                                      w1, b1, g1, be1, w2, b2, g2, be2,
                                      w3, b3, g3, be3, out + cB * cS * 3);
}